// Round 1
// baseline (905.818 us; speedup 1.0000x reference)
//
#include <hip/hip_runtime.h>
#include <hip/hip_bf16.h>

typedef unsigned short u16;
typedef __attribute__((ext_vector_type(8))) short short8;
typedef __attribute__((ext_vector_type(4))) float f32x4;
typedef __attribute__((ext_vector_type(2))) float f32x2;

#define BATCH 32
#define CIN   96
#define LSEQ  4096
#define DIN   256
#define NST   16
#define MROWS (BATCH * LSEQ)   // 131072

__device__ __forceinline__ float b2f(u16 u) {
    union { unsigned int i; float f; } v; v.i = ((unsigned int)u) << 16; return v.f;
}
__device__ __forceinline__ u16 f2b(float f) {
    union { float f; unsigned int i; } v; v.f = f;
    unsigned int i = v.i;
    unsigned int lsb = (i >> 16) & 1u;
    return (u16)((i + 0x7fffu + lsb) >> 16);
}
__device__ __forceinline__ float ldv(const u16* p)   { return b2f(*p); }
__device__ __forceinline__ float ldv(const float* p) { return *p; }
__device__ __forceinline__ void stv(u16* p, float v)   { *p = f2b(v); }
__device__ __forceinline__ void stv(float* p, float v) { *p = v; }

__device__ __forceinline__ void ld8(const u16* p, float* f) {
    short8 v = *(const short8*)p;
    #pragma unroll
    for (int e = 0; e < 8; e++) f[e] = b2f((u16)v[e]);
}
__device__ __forceinline__ void ld8(const float* p, float* f) {
    f32x4 a = *(const f32x4*)p; f32x4 b = *(const f32x4*)(p + 4);
    f[0]=a[0]; f[1]=a[1]; f[2]=a[2]; f[3]=a[3];
    f[4]=b[0]; f[5]=b[1]; f[6]=b[2]; f[7]=b[3];
}

// ---------------------------------------------------------------------------
// K0: fp32 -> bf16 conversion for MFMA weight operands
// ---------------------------------------------------------------------------
__global__ __launch_bounds__(256) void k0_cvt(
    const float* __restrict__ src, u16* __restrict__ dst, int n)
{
    int i = blockIdx.x * 256 + threadIdx.x;
    if (i < n) dst[i] = f2b(src[i]);
}

// ---------------------------------------------------------------------------
// K1: xz[m, 0:512] = h_in[m, 0:96] @ in_proj_w^T + b ; h_in[b*L+l, c] = x[b,c,l]
// ---------------------------------------------------------------------------
__global__ __launch_bounds__(256) void k1_inproj(
    const float* __restrict__ x, const u16* __restrict__ wp,
    const float* __restrict__ bias, u16* __restrict__ xz)
{
    __shared__ u16 AtT[64 * 104];
    int m0 = blockIdx.x * 64;
    int b  = m0 >> 12;
    int l0 = m0 & 4095;
    int n0 = blockIdx.y * 256;
    int t  = threadIdx.x;
    {
        int i = t & 63, c0 = t >> 6;
        for (int c = c0; c < 96; c += 4)
            AtT[i * 104 + c] = f2b(x[((size_t)(b * 96 + c)) * 4096 + l0 + i]);
    }
    __syncthreads();
    int lane = t & 63, wid = t >> 6, q = lane >> 4, ml = lane & 15;
    f32x4 acc[16];
    #pragma unroll
    for (int f = 0; f < 16; f++)
        #pragma unroll
        for (int r = 0; r < 4; r++) acc[f][r] = 0.f;
    int arow = wid * 16 + ml;
    for (int k0 = 0; k0 < 96; k0 += 32) {
        int kb = k0 + q * 8;
        short8 a = *(const short8*)&AtT[arow * 104 + kb];
        #pragma unroll
        for (int f = 0; f < 16; f++) {
            int n = n0 + f * 16 + ml;
            short8 bf = *(const short8*)&wp[(size_t)n * 96 + kb];
            acc[f] = __builtin_amdgcn_mfma_f32_16x16x32_bf16(a, bf, acc[f], 0, 0, 0);
        }
    }
    #pragma unroll
    for (int f = 0; f < 16; f++) {
        int n = n0 + f * 16 + ml;
        float bs = bias[n];
        #pragma unroll
        for (int r = 0; r < 4; r++) {
            int m = m0 + wid * 16 + q * 4 + r;
            xz[(size_t)m * 512 + n] = f2b(acc[f][r] + bs);
        }
    }
}

// ---------------------------------------------------------------------------
// K3f: FUSED conv + x_proj. Per 64-row tile (one batch, 64 consecutive l):
//   u = silu(depthwise causal conv k=4 over x_res)  -> LDS (pitch 264, 2-way
//   free) AND global (needed by k4/k68); then dtbc = u @ x_proj_w^T from LDS,
//   dt = softplus(dt_raw @ dt_proj_w^T + b). Removes old K2 + its u re-read.
// ---------------------------------------------------------------------------
template<typename DT>
__global__ __launch_bounds__(256) void k3_convxproj(
    const u16* __restrict__ xz, const float* __restrict__ cw,
    const float* __restrict__ cb, const u16* __restrict__ xw,
    const float* __restrict__ dw, const float* __restrict__ db,
    u16* __restrict__ u, DT* __restrict__ dt,
    float* __restrict__ Bb, float* __restrict__ Cb)
{
    __shared__ u16 Us[64 * 264];        // 33792 B
    __shared__ float dtbc[64][49];      // 12544 B
    int m0 = blockIdx.x * 64;
    int b  = m0 >> 12;
    int l0 = m0 & 4095;
    int d  = threadIdx.x;
    {   // conv: thread d = channel, 64 rows serial (3-reg shift), halo from xz
        float w0 = cw[d * 4 + 0], w1 = cw[d * 4 + 1];
        float w2 = cw[d * 4 + 2], w3 = cw[d * 4 + 3];
        float bias = cb[d];
        size_t rowbase = ((size_t)b * 4096) * 512 + d;
        size_t ubase   = ((size_t)b * 4096 + l0) * 256 + d;
        float x0 = (l0 >= 3) ? b2f(xz[rowbase + (size_t)(l0 - 3) * 512]) : 0.f;
        float x1 = (l0 >= 2) ? b2f(xz[rowbase + (size_t)(l0 - 2) * 512]) : 0.f;
        float x2 = (l0 >= 1) ? b2f(xz[rowbase + (size_t)(l0 - 1) * 512]) : 0.f;
        #pragma unroll 8
        for (int i = 0; i < 64; i++) {
            float x3 = b2f(xz[rowbase + (size_t)(l0 + i) * 512]);
            float sv = w0 * x0 + w1 * x1 + w2 * x2 + w3 * x3 + bias;
            float sig = 1.f / (1.f + __expf(-sv));
            u16 bv = f2b(sv * sig);
            Us[i * 264 + d] = bv;
            u[ubase + (size_t)i * 256] = bv;
            x0 = x1; x1 = x2; x2 = x3;
        }
    }
    __syncthreads();
    int lane = d & 63, wid = d >> 6, q = lane >> 4, ml = lane & 15;
    f32x4 acc[3];
    #pragma unroll
    for (int f = 0; f < 3; f++)
        #pragma unroll
        for (int r = 0; r < 4; r++) acc[f][r] = 0.f;
    int arow = wid * 16 + ml;
    #pragma unroll
    for (int k0 = 0; k0 < 256; k0 += 32) {
        int kb = k0 + q * 8;
        short8 a = *(const short8*)&Us[arow * 264 + kb];
        #pragma unroll
        for (int f = 0; f < 3; f++) {
            short8 bf = *(const short8*)&xw[(size_t)(f * 16 + ml) * 256 + kb];
            acc[f] = __builtin_amdgcn_mfma_f32_16x16x32_bf16(a, bf, acc[f], 0, 0, 0);
        }
    }
    #pragma unroll
    for (int f = 0; f < 3; f++)
        #pragma unroll
        for (int r = 0; r < 4; r++)
            dtbc[wid * 16 + q * 4 + r][f * 16 + ml] = acc[f][r];
    __syncthreads();
    {   // B, C writes
        int row = d >> 5, cc = d & 31;
        for (int p = 0; p < 8; p++) {
            int rr = row + p * 8;
            float v = dtbc[rr][16 + cc];
            size_t idx = (size_t)(m0 + rr) * 16 + (cc & 15);
            if (cc < 16) Bb[idx] = v; else Cb[idx] = v;
        }
    }
    {   // dt: thread = d
        float wr[16];
        #pragma unroll
        for (int j = 0; j < 16; j++) wr[j] = dw[d * 16 + j];
        float bias = db[d];
        for (int r = 0; r < 64; r++) {
            float s = bias;
            #pragma unroll
            for (int j = 0; j < 16; j++) s += dtbc[r][j] * wr[j];
            float sp = (s > 20.f) ? s : __logf(1.f + __expf(s));
            stv(&dt[(size_t)(m0 + r) * 256 + d], sp);
        }
    }
}

// ---------------------------------------------------------------------------
// K4: scan pass A — per chunk: local final state (h from 0) + sum of dt.
// ---------------------------------------------------------------------------
template<typename DT>
__global__ __launch_bounds__(256) void k4_scanA(
    const DT* __restrict__ dt, const u16* __restrict__ u,
    const float* __restrict__ Bb, const float* __restrict__ alog,
    float* __restrict__ hloc, float* __restrict__ sdt, int lchunk)
{
    __shared__ float Bs[128 * 16];
    int s = blockIdx.x, b = blockIdx.y;
    int l0 = s * lchunk;
    int d = threadIdx.x;
    float Af[16];
    bool structured = true;
    #pragma unroll
    for (int n = 0; n < 16; n++) {
        Af[n] = -__expf(alog[d * 16 + n]);
        structured = structured && (fabsf(Af[n] + (float)(n + 1)) <= 1e-3f * (n + 1));
    }
    const float* bsrc = &Bb[((size_t)b * 4096 + l0) * 16];
    for (int jj = threadIdx.x; jj < lchunk * 16; jj += 256) Bs[jj] = bsrc[jj];
    __syncthreads();
    size_t base = ((size_t)b * 4096 + l0) * 256 + d;
    size_t o = (((size_t)s * 32 + b) * 256 + d) * 16;
    float sd = 0.f;
    if (structured) {
        f32x2 h2[8];
        #pragma unroll
        for (int k = 0; k < 8; k++) h2[k] = (f32x2){0.f, 0.f};
        for (int i = 0; i < lchunk; i++) {
            float dtv = ldv(&dt[base + (size_t)i * 256]);
            float uv  = b2f(u[base + (size_t)i * 256]);
            sd += dtv;
            float du = dtv * uv;
            float e1 = __expf(-dtv);
            float e1s = e1 * e1;
            f32x2 e2 = (f32x2){e1s, e1s};
            f32x2 p  = (f32x2){e1, e1s};
            f32x2 du2 = (f32x2){du, du};
            const f32x2* B2 = (const f32x2*)&Bs[i * 16];
            #pragma unroll
            for (int k = 0; k < 8; k++) {
                h2[k] = p * h2[k] + du2 * B2[k];
                p = p * e2;
            }
        }
        #pragma unroll
        for (int k = 0; k < 8; k++) *(f32x2*)&hloc[o + 2 * k] = h2[k];
    } else {
        float h[16];
        #pragma unroll
        for (int n = 0; n < 16; n++) h[n] = 0.f;
        for (int i = 0; i < lchunk; i++) {
            float dtv = ldv(&dt[base + (size_t)i * 256]);
            float uv  = b2f(u[base + (size_t)i * 256]);
            sd += dtv;
            float du = dtv * uv;
            #pragma unroll
            for (int n = 0; n < 16; n++) {
                float dA = __expf(dtv * Af[n]);
                h[n] = dA * h[n] + du * Bs[i * 16 + n];
            }
        }
        #pragma unroll
        for (int n = 0; n < 16; n++) hloc[o + n] = h[n];
    }
    sdt[((size_t)s * 32 + b) * 256 + d] = sd;
}

// ---------------------------------------------------------------------------
// K5: carry combine across chunks per (b,d,n). hin may alias hloc (in-place:
// per element, hloc is read before hin is written by the same thread).
// ---------------------------------------------------------------------------
__global__ __launch_bounds__(256) void k5_scanB(
    const float* __restrict__ hloc, const float* __restrict__ sdt,
    const float* __restrict__ alog, float* __restrict__ hin, int nch)
{
    int t = blockIdx.x * 256 + threadIdx.x;   // (b, d, n)
    int b = t >> 12;
    int rem = t & 4095;                        // d*16 + n
    int d = rem >> 4;
    float A = -__expf(alog[rem]);
    float h = 0.f;
    for (int s = 0; s < nch; s++) {
        size_t o = ((size_t)(s * 32 + b)) * 4096 + rem;
        float hl = hloc[o];
        float sd = sdt[((size_t)(s * 32 + b)) * 256 + d];
        hin[o] = h;
        h = __expf(A * sd) * h + hl;
    }
}

// ---------------------------------------------------------------------------
// K68: FUSED scan pass C + LN1 + out_proj GEMM + LN2.  One block = (chunk s,
// batch b) = 64 rows x 256 d — exactly the LN/GEMM tile.  The pre-LN1 tensor
// t stays in LDS as fp32 (pitch 260 dwords: frag reads are at the b128
// bandwidth minimum, scan writes / stats reads / epilogue reads are 2-way =
// free).  Stats are exact fp32; MFMA A-fragments are built on the fly as
// f2b((t-mean)*rstd*g1+b1) — bit-identical to the old Yt path; residual uses
// fp32 y1 (slightly MORE accurate than old bf16 Yt readback).
// LDS = 66560 + 4096 + 4096 + 512 = 75264 B -> 2 blocks/CU.
// ---------------------------------------------------------------------------
#define TP 260
template<typename DT>
__global__ __launch_bounds__(256) void k68_scan_final(
    const DT* __restrict__ dt, const u16* __restrict__ u,
    const float* __restrict__ Bb, const float* __restrict__ Cb,
    const float* __restrict__ alog, const float* __restrict__ hin,
    const u16* __restrict__ xz, const float* __restrict__ Dp,
    const u16* __restrict__ ow, const float* __restrict__ ob,
    const float* __restrict__ g1, const float* __restrict__ bb1,
    const float* __restrict__ g2, const float* __restrict__ bb2,
    float* __restrict__ out)
{
    __shared__ float t32[64 * TP];     // 66560 B, fp32 pre-LN1 tile
    __shared__ float Bs[64 * 16];
    __shared__ float Cs[64 * 16];
    __shared__ float mrs[64][2];       // per-row mean, rstd
    int s = blockIdx.x, b = blockIdx.y;
    int l0 = s * 64;
    int d  = threadIdx.x;
    {
        const float* bsrc = &Bb[((size_t)b * 4096 + l0) * 16];
        const float* csrc = &Cb[((size_t)b * 4096 + l0) * 16];
        for (int jj = d; jj < 64 * 16; jj += 256) { Bs[jj] = bsrc[jj]; Cs[jj] = csrc[jj]; }
    }
    __syncthreads();
    // ---- scan phase (thread = column d), t -> LDS fp32
    {
        float Af[16];
        bool structured = true;
        #pragma unroll
        for (int n = 0; n < 16; n++) {
            Af[n] = -__expf(alog[d * 16 + n]);
            structured = structured && (fabsf(Af[n] + (float)(n + 1)) <= 1e-3f * (n + 1));
        }
        size_t o = (((size_t)s * 32 + b) * 256 + d) * 16;
        float Dv = Dp[d];
        size_t base  = ((size_t)b * 4096 + l0) * 256 + d;
        size_t zbase = ((size_t)b * 4096 + l0) * 512 + d;
        if (structured) {
            f32x2 h2[8];
            #pragma unroll
            for (int k = 0; k < 8; k++) h2[k] = *(const f32x2*)&hin[o + 2 * k];
            #pragma unroll 4
            for (int i = 0; i < 64; i++) {
                float dtv = ldv(&dt[base + (size_t)i * 256]);
                float uv  = b2f(u[base + (size_t)i * 256]);
                float du = dtv * uv;
                float e1 = __expf(-dtv);
                float e1s = e1 * e1;
                f32x2 e2 = (f32x2){e1s, e1s};
                f32x2 p  = (f32x2){e1, e1s};
                f32x2 du2 = (f32x2){du, du};
                f32x2 y2 = (f32x2){0.f, 0.f};
                const f32x2* B2 = (const f32x2*)&Bs[i * 16];
                const f32x2* C2 = (const f32x2*)&Cs[i * 16];
                #pragma unroll
                for (int k = 0; k < 8; k++) {
                    h2[k] = p * h2[k] + du2 * B2[k];
                    y2 = y2 + h2[k] * C2[k];
                    p = p * e2;
                }
                float y = y2[0] + y2[1] + uv * Dv;
                float zv = b2f(xz[zbase + (size_t)i * 512 + 256]);
                float xr = b2f(xz[zbase + (size_t)i * 512]);
                float sig = 1.f / (1.f + __expf(-zv));
                y *= zv * sig;
                t32[i * TP + d] = y + xr;
            }
        } else {
            float h[16];
            #pragma unroll
            for (int n = 0; n < 16; n++) h[n] = hin[o + n];
            #pragma unroll 4
            for (int i = 0; i < 64; i++) {
                float dtv = ldv(&dt[base + (size_t)i * 256]);
                float uv  = b2f(u[base + (size_t)i * 256]);
                float du = dtv * uv;
                float y = 0.f;
                #pragma unroll
                for (int n = 0; n < 16; n++) {
                    float dA = __expf(dtv * Af[n]);
                    h[n] = dA * h[n] + du * Bs[i * 16 + n];
                    y += h[n] * Cs[i * 16 + n];
                }
                y += uv * Dv;
                float zv = b2f(xz[zbase + (size_t)i * 512 + 256]);
                float xr = b2f(xz[zbase + (size_t)i * 512]);
                float sig = 1.f / (1.f + __expf(-zv));
                y *= zv * sig;
                t32[i * TP + d] = y + xr;
            }
        }
    }
    __syncthreads();
    // ---- LN1 stats (4 threads/row, exact fp32, same math as old k8)
    {
        int r = d >> 2, c0 = (d & 3) * 64;
        const float* src = &t32[r * TP + c0];
        float sum = 0.f, sq = 0.f;
        #pragma unroll
        for (int jj = 0; jj < 64; jj += 4) {
            f32x4 v = *(const f32x4*)(src + jj);
            #pragma unroll
            for (int e = 0; e < 4; e++) { sum += v[e]; sq += v[e] * v[e]; }
        }
        sum += __shfl_xor(sum, 1); sq += __shfl_xor(sq, 1);
        sum += __shfl_xor(sum, 2); sq += __shfl_xor(sq, 2);
        float mean = sum * (1.f / 256.f);
        float var  = sq * (1.f / 256.f) - mean * mean;
        float rstd = rsqrtf(var + 1e-5f);
        if ((d & 3) == 0) { mrs[r][0] = mean; mrs[r][1] = rstd; }
    }
    __syncthreads();
    // ---- GEMM (A-frags built on the fly from t32) + LN2 epilogue
    int lane = d & 63, wid = d >> 6, q = lane >> 4, ml = lane & 15;
    int arow = wid * 16 + ml;
    float meanA = mrs[arow][0], rstdA = mrs[arow][1];
    const float* trow = &t32[arow * TP];
    f32x4 acc[16];
    #pragma unroll
    for (int f = 0; f < 16; f++)
        #pragma unroll
        for (int r = 0; r < 4; r++) acc[f][r] = 0.f;
    #pragma unroll
    for (int k0 = 0; k0 < 256; k0 += 32) {
        int kb = k0 + q * 8;
        f32x4 ta = *(const f32x4*)(trow + kb);
        f32x4 tb = *(const f32x4*)(trow + kb + 4);
        f32x4 ga = *(const f32x4*)&g1[kb];
        f32x4 gb = *(const f32x4*)&g1[kb + 4];
        f32x4 ba = *(const f32x4*)&bb1[kb];
        f32x4 bbv = *(const f32x4*)&bb1[kb + 4];
        short8 a;
        #pragma unroll
        for (int e = 0; e < 4; e++) {
            a[e]     = (short)f2b((ta[e] - meanA) * rstdA * ga[e] + ba[e]);
            a[e + 4] = (short)f2b((tb[e] - meanA) * rstdA * gb[e] + bbv[e]);
        }
        #pragma unroll
        for (int f = 0; f < 16; f++) {
            short8 bf = *(const short8*)&ow[(size_t)(f * 16 + ml) * 256 + kb];
            acc[f] = __builtin_amdgcn_mfma_f32_16x16x32_bf16(a, bf, acc[f], 0, 0, 0);
        }
    }
    float ps[4] = {0, 0, 0, 0}, psq[4] = {0, 0, 0, 0};
    #pragma unroll
    for (int f = 0; f < 16; f++) {
        int col = f * 16 + ml;
        float obv = ob[col];
        float g1c = g1[col], b1c = bb1[col];
        #pragma unroll
        for (int r = 0; r < 4; r++) {
            int row = wid * 16 + q * 4 + r;
            float y1 = (t32[row * TP + col] - mrs[row][0]) * mrs[row][1] * g1c + b1c;
            float v = acc[f][r] + obv + y1;
            acc[f][r] = v;
            ps[r] += v; psq[r] += v * v;
        }
    }
    #pragma unroll
    for (int msk = 1; msk < 16; msk <<= 1) {
        #pragma unroll
        for (int r = 0; r < 4; r++) {
            ps[r]  += __shfl_xor(ps[r],  msk);
            psq[r] += __shfl_xor(psq[r], msk);
        }
    }
    #pragma unroll
    for (int f = 0; f < 16; f++) {
        int col = f * 16 + ml;
        float g2v = g2[col], b2v = bb2[col];
        #pragma unroll
        for (int r = 0; r < 4; r++) {
            int row = wid * 16 + q * 4 + r;
            float mean = ps[r] * (1.f / 256.f);
            float var  = psq[r] * (1.f / 256.f) - mean * mean;
            float rstd = rsqrtf(var + 1e-5f);
            out[(size_t)(b * 4096 + l0 + row) * 256 + col] = (acc[f][r] - mean) * rstd * g2v + b2v;
        }
    }
}

// ---------------------------------------------------------------------------
// Legacy K6/K8 (fallback path only, when workspace is too small for NC=64)
// ---------------------------------------------------------------------------
template<typename DT, typename TT>
__global__ __launch_bounds__(256) void k6_scanC(
    const DT* __restrict__ dt, const u16* __restrict__ u,
    const float* __restrict__ Bb, const float* __restrict__ Cb,
    const float* __restrict__ alog, const float* __restrict__ hin,
    const u16* __restrict__ xz, const float* __restrict__ Dp,
    TT* __restrict__ tp, int lchunk)
{
    __shared__ float Bs[128 * 16];
    __shared__ float Cs[128 * 16];
    int s = blockIdx.x, b = blockIdx.y;
    int l0 = s * lchunk;
    int d = threadIdx.x;
    float Af[16];
    bool structured = true;
    #pragma unroll
    for (int n = 0; n < 16; n++) {
        Af[n] = -__expf(alog[d * 16 + n]);
        structured = structured && (fabsf(Af[n] + (float)(n + 1)) <= 1e-3f * (n + 1));
    }
    {
        const float* bsrc = &Bb[((size_t)b * 4096 + l0) * 16];
        const float* csrc = &Cb[((size_t)b * 4096 + l0) * 16];
        for (int jj = threadIdx.x; jj < lchunk * 16; jj += 256) {
            Bs[jj] = bsrc[jj]; Cs[jj] = csrc[jj];
        }
    }
    __syncthreads();
    size_t o = (((size_t)s * 32 + b) * 256 + d) * 16;
    float Dv = Dp[d];
    size_t base  = ((size_t)b * 4096 + l0) * 256 + d;
    size_t zbase = ((size_t)b * 4096 + l0) * 512 + d;
    if (structured) {
        f32x2 h2[8];
        #pragma unroll
        for (int k = 0; k < 8; k++) h2[k] = *(const f32x2*)&hin[o + 2 * k];
        for (int i = 0; i < lchunk; i++) {
            float dtv = ldv(&dt[base + (size_t)i * 256]);
            float uv  = b2f(u[base + (size_t)i * 256]);
            float du = dtv * uv;
            float e1 = __expf(-dtv);
            float e1s = e1 * e1;
            f32x2 e2 = (f32x2){e1s, e1s};
            f32x2 p  = (f32x2){e1, e1s};
            f32x2 du2 = (f32x2){du, du};
            f32x2 y2 = (f32x2){0.f, 0.f};
            const f32x2* B2 = (const f32x2*)&Bs[i * 16];
            const f32x2* C2 = (const f32x2*)&Cs[i * 16];
            #pragma unroll
            for (int k = 0; k < 8; k++) {
                h2[k] = p * h2[k] + du2 * B2[k];
                y2 = y2 + h2[k] * C2[k];
                p = p * e2;
            }
            float y = y2[0] + y2[1] + uv * Dv;
            float zv = b2f(xz[zbase + (size_t)i * 512 + 256]);
            float xr = b2f(xz[zbase + (size_t)i * 512]);
            float sig = 1.f / (1.f + __expf(-zv));
            y *= zv * sig;
            stv(&tp[base + (size_t)i * 256], y + xr);
        }
    } else {
        float h[16];
        #pragma unroll
        for (int n = 0; n < 16; n++) h[n] = hin[o + n];
        for (int i = 0; i < lchunk; i++) {
            float dtv = ldv(&dt[base + (size_t)i * 256]);
            float uv  = b2f(u[base + (size_t)i * 256]);
            float du = dtv * uv;
            float y = 0.f;
            #pragma unroll
            for (int n = 0; n < 16; n++) {
                float dA = __expf(dtv * Af[n]);
                h[n] = dA * h[n] + du * Bs[i * 16 + n];
                y += h[n] * Cs[i * 16 + n];
            }
            y += uv * Dv;
            float zv = b2f(xz[zbase + (size_t)i * 512 + 256]);
            float xr = b2f(xz[zbase + (size_t)i * 512]);
            float sig = 1.f / (1.f + __expf(-zv));
            y *= zv * sig;
            stv(&tp[base + (size_t)i * 256], y + xr);
        }
    }
}

template<typename TT>
__global__ __launch_bounds__(256) void k8_final(
    const TT* __restrict__ tb, const u16* __restrict__ ow,
    const float* __restrict__ ob, const float* __restrict__ g1,
    const float* __restrict__ bb1, const float* __restrict__ g2,
    const float* __restrict__ bb2, float* __restrict__ out)
{
    __shared__ u16 Yt[64 * 272];
    int m0 = blockIdx.x * 64;
    int t  = threadIdx.x;
    {
        int r = t >> 2, ccol = (t & 3) * 64;
        const TT* src = &tb[(size_t)(m0 + r) * 256 + ccol];
        u16* dst = &Yt[r * 272 + ccol];
        float sum = 0.f, sq = 0.f;
        for (int jj = 0; jj < 64; jj += 8) {
            float f[8]; ld8(src + jj, f);
            #pragma unroll
            for (int e = 0; e < 8; e++) { sum += f[e]; sq += f[e] * f[e]; }
        }
        sum += __shfl_xor(sum, 1); sq += __shfl_xor(sq, 1);
        sum += __shfl_xor(sum, 2); sq += __shfl_xor(sq, 2);
        float mean = sum * (1.f / 256.f);
        float var  = sq * (1.f / 256.f) - mean * mean;
        float rstd = rsqrtf(var + 1e-5f);
        for (int jj = 0; jj < 64; jj += 8) {
            float f[8]; ld8(src + jj, f);
            #pragma unroll
            for (int e = 0; e < 8; e++) {
                int c = ccol + jj + e;
                dst[jj + e] = f2b((f[e] - mean) * rstd * g1[c] + bb1[c]);
            }
        }
    }
    __syncthreads();
    int lane = t & 63, wid = t >> 6, q = lane >> 4, ml = lane & 15;
    f32x4 acc[16];
    #pragma unroll
    for (int f = 0; f < 16; f++)
        #pragma unroll
        for (int r = 0; r < 4; r++) acc[f][r] = 0.f;
    int arow = wid * 16 + ml;
    #pragma unroll
    for (int k0 = 0; k0 < 256; k0 += 32) {
        short8 a = *(const short8*)&Yt[arow * 272 + k0 + q * 8];
        #pragma unroll
        for (int f = 0; f < 16; f++) {
            short8 bf = *(const short8*)&ow[(size_t)(f * 16 + ml) * 256 + k0 + q * 8];
            acc[f] = __builtin_amdgcn_mfma_f32_16x16x32_bf16(a, bf, acc[f], 0, 0, 0);
        }
    }
    float ps[4] = {0, 0, 0, 0}, psq[4] = {0, 0, 0, 0};
    #pragma unroll
    for (int f = 0; f < 16; f++) {
        int col = f * 16 + ml;
        float obv = ob[col];
        #pragma unroll
        for (int r = 0; r < 4; r++) {
            int row = wid * 16 + q * 4 + r;
            float v = acc[f][r] + obv + b2f(Yt[row * 272 + col]);
            acc[f][r] = v;
            ps[r] += v; psq[r] += v * v;
        }
    }
    #pragma unroll
    for (int msk = 1; msk < 16; msk <<= 1) {
        #pragma unroll
        for (int r = 0; r < 4; r++) {
            ps[r]  += __shfl_xor(ps[r],  msk);
            psq[r] += __shfl_xor(psq[r], msk);
        }
    }
    #pragma unroll
    for (int f = 0; f < 16; f++) {
        int col = f * 16 + ml;
        float g2v = g2[col], b2v = bb2[col];
        #pragma unroll
        for (int r = 0; r < 4; r++) {
            int row = wid * 16 + q * 4 + r;
            float mean = ps[r] * (1.f / 256.f);
            float var  = psq[r] * (1.f / 256.f) - mean * mean;
            float rstd = rsqrtf(var + 1e-5f);
            out[(size_t)(m0 + row) * 256 + col] = (acc[f][r] - mean) * rstd * g2v + b2v;
        }
    }
}

extern "C" void kernel_launch(void* const* d_in, const int* in_sizes, int n_in,
                              void* d_out, int out_size, void* d_ws, size_t ws_size,
                              hipStream_t stream)
{
    const float* x    = (const float*)d_in[0];
    const float* ipw  = (const float*)d_in[1];
    const float* ipb  = (const float*)d_in[2];
    const float* cw   = (const float*)d_in[3];
    const float* cb   = (const float*)d_in[4];
    const float* xpw  = (const float*)d_in[5];
    const float* dpw  = (const float*)d_in[6];
    const float* dpb  = (const float*)d_in[7];
    const float* opw  = (const float*)d_in[8];
    const float* opb  = (const float*)d_in[9];
    const float* alog = (const float*)d_in[10];
    const float* Dp   = (const float*)d_in[11];
    const float* g1   = (const float*)d_in[12];
    const float* b1   = (const float*)d_in[13];
    const float* g2   = (const float*)d_in[14];
    const float* b2   = (const float*)d_in[15];
    float* outp = (float*)d_out;

    char* ws = (char*)d_ws;
    u16*   xz  = (u16*)ws;                          // 134217728 B
    u16*   u   = (u16*)(ws + 134217728);            //  67108864 B
    float* Bb  = (float*)(ws + 201326592);          //   8388608 B
    float* Cb  = (float*)(ws + 209715200);          //   8388608 B
    u16* ipw_b = (u16*)(ws + 218103808);            // 49152 el
    u16* xpw_b = ipw_b + 49152;                     // 12288 el
    u16* opw_b = xpw_b + 12288;                     // 65536 el
    const size_t wbase = 218103808 + 262144;        // weights padded

    k0_cvt<<<192, 256, 0, stream>>>(ipw, ipw_b, 49152);
    k0_cvt<<<48,  256, 0, stream>>>(xpw, xpw_b, 12288);
    k0_cvt<<<256, 256, 0, stream>>>(opw, opw_b, 65536);
    k1_inproj<<<dim3(2048, 2), 256, 0, stream>>>(x, ipw_b, ipb, xz);

    // scan scratch with in-place carry (hin aliases hloc): hloc + sdt only
    const size_t scan64 = (size_t)64 * 524288 + (size_t)64 * 32768;   // 35.6 MB

    if (ws_size >= wbase + 134217728 + scan64) {
        // fused path, fp32 dt
        float* dt   = (float*)(ws + wbase);
        float* hloc = (float*)(ws + wbase + 134217728);
        float* sdt  = hloc + (size_t)64 * 131072;
        k3_convxproj<float><<<2048, 256, 0, stream>>>(xz, cw, cb, xpw_b, dpw, dpb, u, dt, Bb, Cb);
        k4_scanA<float><<<dim3(64, 32), 256, 0, stream>>>(dt, u, Bb, alog, hloc, sdt, 64);
        k5_scanB<<<512, 256, 0, stream>>>(hloc, sdt, alog, hloc, 64);
        k68_scan_final<float><<<dim3(64, 32), 256, 0, stream>>>(
            dt, u, Bb, Cb, alog, hloc, xz, Dp, opw_b, opb, g1, b1, g2, b2, outp);
    } else if (ws_size >= wbase + 67108864 + scan64) {
        // fused path, bf16 dt
        u16*   dt   = (u16*)(ws + wbase);
        float* hloc = (float*)(ws + wbase + 67108864);
        float* sdt  = hloc + (size_t)64 * 131072;
        k3_convxproj<u16><<<2048, 256, 0, stream>>>(xz, cw, cb, xpw_b, dpw, dpb, u, dt, Bb, Cb);
        k4_scanA<u16><<<dim3(64, 32), 256, 0, stream>>>(dt, u, Bb, alog, hloc, sdt, 64);
        k5_scanB<<<512, 256, 0, stream>>>(hloc, sdt, alog, hloc, 64);
        k68_scan_final<u16><<<dim3(64, 32), 256, 0, stream>>>(
            dt, u, Bb, Cb, alog, hloc, xz, Dp, opw_b, opb, g1, b1, g2, b2, outp);
    } else {
        // legacy fallback: NC=32, bf16 dt, t written in-place over u
        u16*   dt   = (u16*)(ws + wbase);
        float* hloc = (float*)(ws + wbase + 67108864);
        float* sdt  = hloc + (size_t)32 * 131072;
        k3_convxproj<u16><<<2048, 256, 0, stream>>>(xz, cw, cb, xpw_b, dpw, dpb, u, dt, Bb, Cb);
        k4_scanA<u16><<<dim3(32, 32), 256, 0, stream>>>(dt, u, Bb, alog, hloc, sdt, 128);
        k5_scanB<<<512, 256, 0, stream>>>(hloc, sdt, alog, hloc, 32);
        k6_scanC<u16, u16><<<dim3(32, 32), 256, 0, stream>>>(dt, u, Bb, Cb, alog, hloc, xz, Dp, u, 128);
        k8_final<u16><<<2048, 256, 0, stream>>>(u, opw_b, opb, g1, b1, g2, b2, outp);
    }
}

// Round 3
// 897.959 us; speedup vs baseline: 1.0088x; 1.0088x over previous
//
#include <hip/hip_runtime.h>
#include <hip/hip_bf16.h>

typedef unsigned short u16;
typedef __attribute__((ext_vector_type(8))) short short8;
typedef __attribute__((ext_vector_type(4))) float f32x4;
typedef __attribute__((ext_vector_type(2))) float f32x2;

#define BATCH 32
#define CIN   96
#define LSEQ  4096
#define DIN   256
#define NST   16
#define MROWS (BATCH * LSEQ)   // 131072

__device__ __forceinline__ float b2f(u16 u) {
    union { unsigned int i; float f; } v; v.i = ((unsigned int)u) << 16; return v.f;
}
__device__ __forceinline__ u16 f2b(float f) {
    union { float f; unsigned int i; } v; v.f = f;
    unsigned int i = v.i;
    unsigned int lsb = (i >> 16) & 1u;
    return (u16)((i + 0x7fffu + lsb) >> 16);
}
__device__ __forceinline__ float ldv(const u16* p)   { return b2f(*p); }
__device__ __forceinline__ float ldv(const float* p) { return *p; }
__device__ __forceinline__ void stv(u16* p, float v)   { *p = f2b(v); }
__device__ __forceinline__ void stv(float* p, float v) { *p = v; }

__device__ __forceinline__ void ld8(const u16* p, float* f) {
    short8 v = *(const short8*)p;
    #pragma unroll
    for (int e = 0; e < 8; e++) f[e] = b2f((u16)v[e]);
}
__device__ __forceinline__ void ld8(const float* p, float* f) {
    f32x4 a = *(const f32x4*)p; f32x4 b = *(const f32x4*)(p + 4);
    f[0]=a[0]; f[1]=a[1]; f[2]=a[2]; f[3]=a[3];
    f[4]=b[0]; f[5]=b[1]; f[6]=b[2]; f[7]=b[3];
}

// ---------------------------------------------------------------------------
// K0: fp32 -> bf16 conversion for MFMA weight operands
// ---------------------------------------------------------------------------
__global__ __launch_bounds__(256) void k0_cvt(
    const float* __restrict__ src, u16* __restrict__ dst, int n)
{
    int i = blockIdx.x * 256 + threadIdx.x;
    if (i < n) dst[i] = f2b(src[i]);
}

// ---------------------------------------------------------------------------
// K1: xz[m, 0:512] = h_in[m, 0:96] @ in_proj_w^T + b ; h_in[b*L+l, c] = x[b,c,l]
// ---------------------------------------------------------------------------
__global__ __launch_bounds__(256) void k1_inproj(
    const float* __restrict__ x, const u16* __restrict__ wp,
    const float* __restrict__ bias, u16* __restrict__ xz)
{
    __shared__ u16 AtT[64 * 104];
    int m0 = blockIdx.x * 64;
    int b  = m0 >> 12;
    int l0 = m0 & 4095;
    int n0 = blockIdx.y * 256;
    int t  = threadIdx.x;
    {
        int i = t & 63, c0 = t >> 6;
        for (int c = c0; c < 96; c += 4)
            AtT[i * 104 + c] = f2b(x[((size_t)(b * 96 + c)) * 4096 + l0 + i]);
    }
    __syncthreads();
    int lane = t & 63, wid = t >> 6, q = lane >> 4, ml = lane & 15;
    f32x4 acc[16];
    #pragma unroll
    for (int f = 0; f < 16; f++)
        #pragma unroll
        for (int r = 0; r < 4; r++) acc[f][r] = 0.f;
    int arow = wid * 16 + ml;
    for (int k0 = 0; k0 < 96; k0 += 32) {
        int kb = k0 + q * 8;
        short8 a = *(const short8*)&AtT[arow * 104 + kb];
        #pragma unroll
        for (int f = 0; f < 16; f++) {
            int n = n0 + f * 16 + ml;
            short8 bf = *(const short8*)&wp[(size_t)n * 96 + kb];
            acc[f] = __builtin_amdgcn_mfma_f32_16x16x32_bf16(a, bf, acc[f], 0, 0, 0);
        }
    }
    #pragma unroll
    for (int f = 0; f < 16; f++) {
        int n = n0 + f * 16 + ml;
        float bs = bias[n];
        #pragma unroll
        for (int r = 0; r < 4; r++) {
            int m = m0 + wid * 16 + q * 4 + r;
            xz[(size_t)m * 512 + n] = f2b(acc[f][r] + bs);
        }
    }
}

// ---------------------------------------------------------------------------
// K3f: FUSED conv + x_proj. Per 64-row tile (one batch, 64 consecutive l):
//   u = silu(depthwise causal conv k=4 over x_res) -> LDS AND global; then
//   dtbc = u @ x_proj_w^T from LDS, dt = softplus(dt_raw @ dt_proj_w^T + b).
// ---------------------------------------------------------------------------
template<typename DT>
__global__ __launch_bounds__(256) void k3_convxproj(
    const u16* __restrict__ xz, const float* __restrict__ cw,
    const float* __restrict__ cb, const u16* __restrict__ xw,
    const float* __restrict__ dw, const float* __restrict__ db,
    u16* __restrict__ u, DT* __restrict__ dt,
    float* __restrict__ Bb, float* __restrict__ Cb)
{
    __shared__ u16 Us[64 * 264];        // 33792 B
    __shared__ float dtbc[64][49];      // 12544 B
    int m0 = blockIdx.x * 64;
    int b  = m0 >> 12;
    int l0 = m0 & 4095;
    int d  = threadIdx.x;
    {   // conv: thread d = channel, 64 rows serial (3-reg shift), halo from xz
        float w0 = cw[d * 4 + 0], w1 = cw[d * 4 + 1];
        float w2 = cw[d * 4 + 2], w3 = cw[d * 4 + 3];
        float bias = cb[d];
        size_t rowbase = ((size_t)b * 4096) * 512 + d;
        size_t ubase   = ((size_t)b * 4096 + l0) * 256 + d;
        float x0 = (l0 >= 3) ? b2f(xz[rowbase + (size_t)(l0 - 3) * 512]) : 0.f;
        float x1 = (l0 >= 2) ? b2f(xz[rowbase + (size_t)(l0 - 2) * 512]) : 0.f;
        float x2 = (l0 >= 1) ? b2f(xz[rowbase + (size_t)(l0 - 1) * 512]) : 0.f;
        #pragma unroll 8
        for (int i = 0; i < 64; i++) {
            float x3 = b2f(xz[rowbase + (size_t)(l0 + i) * 512]);
            float sv = w0 * x0 + w1 * x1 + w2 * x2 + w3 * x3 + bias;
            float sig = 1.f / (1.f + __expf(-sv));
            u16 bv = f2b(sv * sig);
            Us[i * 264 + d] = bv;
            u[ubase + (size_t)i * 256] = bv;
            x0 = x1; x1 = x2; x2 = x3;
        }
    }
    __syncthreads();
    int lane = d & 63, wid = d >> 6, q = lane >> 4, ml = lane & 15;
    f32x4 acc[3];
    #pragma unroll
    for (int f = 0; f < 3; f++)
        #pragma unroll
        for (int r = 0; r < 4; r++) acc[f][r] = 0.f;
    int arow = wid * 16 + ml;
    #pragma unroll
    for (int k0 = 0; k0 < 256; k0 += 32) {
        int kb = k0 + q * 8;
        short8 a = *(const short8*)&Us[arow * 264 + kb];
        #pragma unroll
        for (int f = 0; f < 3; f++) {
            short8 bf = *(const short8*)&xw[(size_t)(f * 16 + ml) * 256 + kb];
            acc[f] = __builtin_amdgcn_mfma_f32_16x16x32_bf16(a, bf, acc[f], 0, 0, 0);
        }
    }
    #pragma unroll
    for (int f = 0; f < 3; f++)
        #pragma unroll
        for (int r = 0; r < 4; r++)
            dtbc[wid * 16 + q * 4 + r][f * 16 + ml] = acc[f][r];
    __syncthreads();
    {   // B, C writes
        int row = d >> 5, cc = d & 31;
        for (int p = 0; p < 8; p++) {
            int rr = row + p * 8;
            float v = dtbc[rr][16 + cc];
            size_t idx = (size_t)(m0 + rr) * 16 + (cc & 15);
            if (cc < 16) Bb[idx] = v; else Cb[idx] = v;
        }
    }
    {   // dt: thread = d
        float wr[16];
        #pragma unroll
        for (int j = 0; j < 16; j++) wr[j] = dw[d * 16 + j];
        float bias = db[d];
        for (int r = 0; r < 64; r++) {
            float s = bias;
            #pragma unroll
            for (int j = 0; j < 16; j++) s += dtbc[r][j] * wr[j];
            float sp = (s > 20.f) ? s : __logf(1.f + __expf(s));
            stv(&dt[(size_t)(m0 + r) * 256 + d], sp);
        }
    }
}

// ---------------------------------------------------------------------------
// K4: scan pass A — per chunk: local final state (h from 0) + sum of dt.
// ---------------------------------------------------------------------------
template<typename DT>
__global__ __launch_bounds__(256) void k4_scanA(
    const DT* __restrict__ dt, const u16* __restrict__ u,
    const float* __restrict__ Bb, const float* __restrict__ alog,
    float* __restrict__ hloc, float* __restrict__ sdt, int lchunk)
{
    __shared__ float Bs[128 * 16];
    int s = blockIdx.x, b = blockIdx.y;
    int l0 = s * lchunk;
    int d = threadIdx.x;
    float Af[16];
    bool structured = true;
    #pragma unroll
    for (int n = 0; n < 16; n++) {
        Af[n] = -__expf(alog[d * 16 + n]);
        structured = structured && (fabsf(Af[n] + (float)(n + 1)) <= 1e-3f * (n + 1));
    }
    const float* bsrc = &Bb[((size_t)b * 4096 + l0) * 16];
    for (int jj = threadIdx.x; jj < lchunk * 16; jj += 256) Bs[jj] = bsrc[jj];
    __syncthreads();
    size_t base = ((size_t)b * 4096 + l0) * 256 + d;
    size_t o = (((size_t)s * 32 + b) * 256 + d) * 16;
    float sd = 0.f;
    if (structured) {
        f32x2 h2[8];
        #pragma unroll
        for (int k = 0; k < 8; k++) h2[k] = (f32x2){0.f, 0.f};
        for (int i = 0; i < lchunk; i++) {
            float dtv = ldv(&dt[base + (size_t)i * 256]);
            float uv  = b2f(u[base + (size_t)i * 256]);
            sd += dtv;
            float du = dtv * uv;
            float e1 = __expf(-dtv);
            float e1s = e1 * e1;
            f32x2 e2 = (f32x2){e1s, e1s};
            f32x2 p  = (f32x2){e1, e1s};
            f32x2 du2 = (f32x2){du, du};
            const f32x2* B2 = (const f32x2*)&Bs[i * 16];
            #pragma unroll
            for (int k = 0; k < 8; k++) {
                h2[k] = p * h2[k] + du2 * B2[k];
                p = p * e2;
            }
        }
        #pragma unroll
        for (int k = 0; k < 8; k++) *(f32x2*)&hloc[o + 2 * k] = h2[k];
    } else {
        float h[16];
        #pragma unroll
        for (int n = 0; n < 16; n++) h[n] = 0.f;
        for (int i = 0; i < lchunk; i++) {
            float dtv = ldv(&dt[base + (size_t)i * 256]);
            float uv  = b2f(u[base + (size_t)i * 256]);
            sd += dtv;
            float du = dtv * uv;
            #pragma unroll
            for (int n = 0; n < 16; n++) {
                float dA = __expf(dtv * Af[n]);
                h[n] = dA * h[n] + du * Bs[i * 16 + n];
            }
        }
        #pragma unroll
        for (int n = 0; n < 16; n++) hloc[o + n] = h[n];
    }
    sdt[((size_t)s * 32 + b) * 256 + d] = sd;
}

// ---------------------------------------------------------------------------
// K5: carry combine across chunks per (b,d,n). hin aliases hloc (in-place:
// per element, hloc is read before hin is written by the same thread).
// ---------------------------------------------------------------------------
__global__ __launch_bounds__(256) void k5_scanB(
    const float* __restrict__ hloc, const float* __restrict__ sdt,
    const float* __restrict__ alog, float* __restrict__ hin, int nch)
{
    int t = blockIdx.x * 256 + threadIdx.x;   // (b, d, n)
    int b = t >> 12;
    int rem = t & 4095;                        // d*16 + n
    int d = rem >> 4;
    float A = -__expf(alog[rem]);
    float h = 0.f;
    for (int s = 0; s < nch; s++) {
        size_t o = ((size_t)(s * 32 + b)) * 4096 + rem;
        float hl = hloc[o];
        float sd = sdt[((size_t)(s * 32 + b)) * 256 + d];
        hin[o] = h;
        h = __expf(A * sd) * h + hl;
    }
}

// ---------------------------------------------------------------------------
// K6: scan pass C — true scan with carry-in; fuse y+u*D, *silu(z), +x_res.
// Writes pre-LN1 tensor t (u16, in-place over u).
// ---------------------------------------------------------------------------
template<typename DT, typename TT>
__global__ __launch_bounds__(256) void k6_scanC(
    const DT* __restrict__ dt, const u16* __restrict__ u,
    const float* __restrict__ Bb, const float* __restrict__ Cb,
    const float* __restrict__ alog, const float* __restrict__ hin,
    const u16* __restrict__ xz, const float* __restrict__ Dp,
    TT* __restrict__ tp, int lchunk)
{
    __shared__ float Bs[128 * 16];
    __shared__ float Cs[128 * 16];
    int s = blockIdx.x, b = blockIdx.y;
    int l0 = s * lchunk;
    int d = threadIdx.x;
    float Af[16];
    bool structured = true;
    #pragma unroll
    for (int n = 0; n < 16; n++) {
        Af[n] = -__expf(alog[d * 16 + n]);
        structured = structured && (fabsf(Af[n] + (float)(n + 1)) <= 1e-3f * (n + 1));
    }
    {
        const float* bsrc = &Bb[((size_t)b * 4096 + l0) * 16];
        const float* csrc = &Cb[((size_t)b * 4096 + l0) * 16];
        for (int jj = threadIdx.x; jj < lchunk * 16; jj += 256) {
            Bs[jj] = bsrc[jj]; Cs[jj] = csrc[jj];
        }
    }
    __syncthreads();
    size_t o = (((size_t)s * 32 + b) * 256 + d) * 16;
    float Dv = Dp[d];
    size_t base  = ((size_t)b * 4096 + l0) * 256 + d;
    size_t zbase = ((size_t)b * 4096 + l0) * 512 + d;
    if (structured) {
        f32x2 h2[8];
        #pragma unroll
        for (int k = 0; k < 8; k++) h2[k] = *(const f32x2*)&hin[o + 2 * k];
        for (int i = 0; i < lchunk; i++) {
            float dtv = ldv(&dt[base + (size_t)i * 256]);
            float uv  = b2f(u[base + (size_t)i * 256]);
            float du = dtv * uv;
            float e1 = __expf(-dtv);
            float e1s = e1 * e1;
            f32x2 e2 = (f32x2){e1s, e1s};
            f32x2 p  = (f32x2){e1, e1s};
            f32x2 du2 = (f32x2){du, du};
            f32x2 y2 = (f32x2){0.f, 0.f};
            const f32x2* B2 = (const f32x2*)&Bs[i * 16];
            const f32x2* C2 = (const f32x2*)&Cs[i * 16];
            #pragma unroll
            for (int k = 0; k < 8; k++) {
                h2[k] = p * h2[k] + du2 * B2[k];
                y2 = y2 + h2[k] * C2[k];
                p = p * e2;
            }
            float y = y2[0] + y2[1] + uv * Dv;
            float zv = b2f(xz[zbase + (size_t)i * 512 + 256]);
            float xr = b2f(xz[zbase + (size_t)i * 512]);
            float sig = 1.f / (1.f + __expf(-zv));
            y *= zv * sig;
            stv(&tp[base + (size_t)i * 256], y + xr);
        }
    } else {
        float h[16];
        #pragma unroll
        for (int n = 0; n < 16; n++) h[n] = hin[o + n];
        for (int i = 0; i < lchunk; i++) {
            float dtv = ldv(&dt[base + (size_t)i * 256]);
            float uv  = b2f(u[base + (size_t)i * 256]);
            float du = dtv * uv;
            float y = 0.f;
            #pragma unroll
            for (int n = 0; n < 16; n++) {
                float dA = __expf(dtv * Af[n]);
                h[n] = dA * h[n] + du * Bs[i * 16 + n];
                y += h[n] * Cs[i * 16 + n];
            }
            y += uv * Dv;
            float zv = b2f(xz[zbase + (size_t)i * 512 + 256]);
            float xr = b2f(xz[zbase + (size_t)i * 512]);
            float sig = 1.f / (1.f + __expf(-zv));
            y *= zv * sig;
            stv(&tp[base + (size_t)i * 256], y + xr);
        }
    }
}

// ---------------------------------------------------------------------------
// K8: y1 = LN1(t); y_proj = y1 @ out_proj_w^T + ob; out = LN2(y1 + y_proj).
// Yt is XOR-swizzled [64][256] u16 = 32768 B exactly: byte ^= (row&7)<<4
// (bitwise value-identical to the unswizzled round-0 kernel; only LDS
// addressing differs). 5 blocks/CU fill the 160 KiB LDS pool exactly;
// __launch_bounds__(256,5) asks the allocator for <=102 VGPR to match.
// ---------------------------------------------------------------------------
#define YSWZ(bo, row) ((bo) ^ (((row) & 7) << 4))
template<typename TT>
__global__ __launch_bounds__(256, 5) void k8_final(
    const TT* __restrict__ tb, const u16* __restrict__ ow,
    const float* __restrict__ ob, const float* __restrict__ g1,
    const float* __restrict__ bb1, const float* __restrict__ g2,
    const float* __restrict__ bb2, float* __restrict__ out)
{
    __shared__ u16 Yt[64 * 256];       // 32768 B, swizzled
    char* Yb = (char*)Yt;
    int m0 = blockIdx.x * 64;
    int t  = threadIdx.x;
    {   // LN1 (4 threads per row, shuffle-combine partials)
        int r = t >> 2, ccol = (t & 3) * 64;
        const TT* src = &tb[(size_t)(m0 + r) * 256 + ccol];
        float sum = 0.f, sq = 0.f;
        for (int jj = 0; jj < 64; jj += 8) {
            float f[8]; ld8(src + jj, f);
            #pragma unroll
            for (int e = 0; e < 8; e++) { sum += f[e]; sq += f[e] * f[e]; }
        }
        sum += __shfl_xor(sum, 1); sq += __shfl_xor(sq, 1);
        sum += __shfl_xor(sum, 2); sq += __shfl_xor(sq, 2);
        float mean = sum * (1.f / 256.f);
        float var  = sq * (1.f / 256.f) - mean * mean;
        float rstd = rsqrtf(var + 1e-5f);
        for (int jj = 0; jj < 64; jj += 8) {
            float f[8]; ld8(src + jj, f);
            short8 v;
            #pragma unroll
            for (int e = 0; e < 8; e++) {
                int c = ccol + jj + e;
                v[e] = (short)f2b((f[e] - mean) * rstd * g1[c] + bb1[c]);
            }
            int bo = r * 512 + (ccol + jj) * 2;
            *(short8*)(Yb + YSWZ(bo, r)) = v;
        }
    }
    __syncthreads();
    int lane = t & 63, wid = t >> 6, q = lane >> 4, ml = lane & 15;
    f32x4 acc[16];
    #pragma unroll
    for (int f = 0; f < 16; f++)
        #pragma unroll
        for (int r = 0; r < 4; r++) acc[f][r] = 0.f;
    int arow = wid * 16 + ml;
    #pragma unroll
    for (int k0 = 0; k0 < 256; k0 += 32) {
        int bo = arow * 512 + (k0 + q * 8) * 2;
        short8 a = *(const short8*)(Yb + YSWZ(bo, arow));
        #pragma unroll
        for (int f = 0; f < 16; f++) {
            short8 bf = *(const short8*)&ow[(size_t)(f * 16 + ml) * 256 + k0 + q * 8];
            acc[f] = __builtin_amdgcn_mfma_f32_16x16x32_bf16(a, bf, acc[f], 0, 0, 0);
        }
    }
    float ps[4] = {0, 0, 0, 0}, psq[4] = {0, 0, 0, 0};
    #pragma unroll
    for (int f = 0; f < 16; f++) {
        int col = f * 16 + ml;
        float obv = ob[col];
        #pragma unroll
        for (int r = 0; r < 4; r++) {
            int row = wid * 16 + q * 4 + r;
            int bo = row * 512 + col * 2;
            float y1 = b2f(*(const u16*)(Yb + YSWZ(bo, row)));
            float v = acc[f][r] + obv + y1;
            acc[f][r] = v;
            ps[r] += v; psq[r] += v * v;
        }
    }
    #pragma unroll
    for (int msk = 1; msk < 16; msk <<= 1) {
        #pragma unroll
        for (int r = 0; r < 4; r++) {
            ps[r]  += __shfl_xor(ps[r],  msk);
            psq[r] += __shfl_xor(psq[r], msk);
        }
    }
    #pragma unroll
    for (int f = 0; f < 16; f++) {
        int col = f * 16 + ml;
        float g2v = g2[col], b2v = bb2[col];
        #pragma unroll
        for (int r = 0; r < 4; r++) {
            int row = wid * 16 + q * 4 + r;
            float mean = ps[r] * (1.f / 256.f);
            float var  = psq[r] * (1.f / 256.f) - mean * mean;
            float rstd = rsqrtf(var + 1e-5f);
            out[(size_t)(m0 + row) * 256 + col] = (acc[f][r] - mean) * rstd * g2v + b2v;
        }
    }
}

extern "C" void kernel_launch(void* const* d_in, const int* in_sizes, int n_in,
                              void* d_out, int out_size, void* d_ws, size_t ws_size,
                              hipStream_t stream)
{
    const float* x    = (const float*)d_in[0];
    const float* ipw  = (const float*)d_in[1];
    const float* ipb  = (const float*)d_in[2];
    const float* cw   = (const float*)d_in[3];
    const float* cb   = (const float*)d_in[4];
    const float* xpw  = (const float*)d_in[5];
    const float* dpw  = (const float*)d_in[6];
    const float* dpb  = (const float*)d_in[7];
    const float* opw  = (const float*)d_in[8];
    const float* opb  = (const float*)d_in[9];
    const float* alog = (const float*)d_in[10];
    const float* Dp   = (const float*)d_in[11];
    const float* g1   = (const float*)d_in[12];
    const float* b1   = (const float*)d_in[13];
    const float* g2   = (const float*)d_in[14];
    const float* b2   = (const float*)d_in[15];
    float* outp = (float*)d_out;

    char* ws = (char*)d_ws;
    u16*   xz  = (u16*)ws;                          // 134217728 B
    u16*   u   = (u16*)(ws + 134217728);            //  67108864 B
    float* Bb  = (float*)(ws + 201326592);          //   8388608 B
    float* Cb  = (float*)(ws + 209715200);          //   8388608 B
    u16* ipw_b = (u16*)(ws + 218103808);            // 49152 el
    u16* xpw_b = ipw_b + 49152;                     // 12288 el
    u16* opw_b = xpw_b + 12288;                     // 65536 el
    const size_t wbase = 218103808 + 262144;        // weights padded

    k0_cvt<<<192, 256, 0, stream>>>(ipw, ipw_b, 49152);
    k0_cvt<<<48,  256, 0, stream>>>(xpw, xpw_b, 12288);
    k0_cvt<<<256, 256, 0, stream>>>(opw, opw_b, 65536);
    k1_inproj<<<dim3(2048, 2), 256, 0, stream>>>(x, ipw_b, ipb, xz);

    // scan scratch with in-place carry (hin aliases hloc): hloc + sdt only
    const size_t scan64 = (size_t)64 * 524288 + (size_t)64 * 32768;   // 35.6 MB

    // NOTE: no fp32-t tier — pipeline numerics pinned to the round-0-verified
    // path (fp32 dt -> bf16 t in-place over u -> k8<u16>, absmax 0.1914).
    if (ws_size >= wbase + 134217728 + scan64) {
        // fp32 dt, bf16 t in-place over u
        float* dt   = (float*)(ws + wbase);
        float* hloc = (float*)(ws + wbase + 134217728);
        float* sdt  = hloc + (size_t)64 * 131072;
        k3_convxproj<float><<<2048, 256, 0, stream>>>(xz, cw, cb, xpw_b, dpw, dpb, u, dt, Bb, Cb);
        k4_scanA<float><<<dim3(64, 32), 256, 0, stream>>>(dt, u, Bb, alog, hloc, sdt, 64);
        k5_scanB<<<512, 256, 0, stream>>>(hloc, sdt, alog, hloc, 64);
        k6_scanC<float, u16><<<dim3(64, 32), 256, 0, stream>>>(dt, u, Bb, Cb, alog, hloc, xz, Dp, u, 64);
        k8_final<u16><<<2048, 256, 0, stream>>>(u, opw_b, opb, g1, b1, g2, b2, outp);
    } else if (ws_size >= wbase + 67108864 + scan64) {
        // bf16 dt, bf16 t in-place over u
        u16*   dt   = (u16*)(ws + wbase);
        float* hloc = (float*)(ws + wbase + 67108864);
        float* sdt  = hloc + (size_t)64 * 131072;
        k3_convxproj<u16><<<2048, 256, 0, stream>>>(xz, cw, cb, xpw_b, dpw, dpb, u, dt, Bb, Cb);
        k4_scanA<u16><<<dim3(64, 32), 256, 0, stream>>>(dt, u, Bb, alog, hloc, sdt, 64);
        k5_scanB<<<512, 256, 0, stream>>>(hloc, sdt, alog, hloc, 64);
        k6_scanC<u16, u16><<<dim3(64, 32), 256, 0, stream>>>(dt, u, Bb, Cb, alog, hloc, xz, Dp, u, 64);
        k8_final<u16><<<2048, 256, 0, stream>>>(u, opw_b, opb, g1, b1, g2, b2, outp);
    } else {
        // legacy fallback: NC=32, bf16 dt, t in-place over u
        u16*   dt   = (u16*)(ws + wbase);
        float* hloc = (float*)(ws + wbase + 67108864);
        float* sdt  = hloc + (size_t)32 * 131072;
        k3_convxproj<u16><<<2048, 256, 0, stream>>>(xz, cw, cb, xpw_b, dpw, dpb, u, dt, Bb, Cb);
        k4_scanA<u16><<<dim3(32, 32), 256, 0, stream>>>(dt, u, Bb, alog, hloc, sdt, 128);
        k5_scanB<<<512, 256, 0, stream>>>(hloc, sdt, alog, hloc, 32);
        k6_scanC<u16, u16><<<dim3(32, 32), 256, 0, stream>>>(dt, u, Bb, Cb, alog, hloc, xz, Dp, u, 128);
        k8_final<u16><<<2048, 256, 0, stream>>>(u, opw_b, opb, g1, b1, g2, b2, outp);
    }
}

// Round 8
// 739.955 us; speedup vs baseline: 1.2242x; 1.2135x over previous
//
#include <hip/hip_runtime.h>
#include <hip/hip_bf16.h>

typedef unsigned short u16;
typedef __attribute__((ext_vector_type(8))) short short8;
typedef __attribute__((ext_vector_type(4))) float f32x4;
typedef __attribute__((ext_vector_type(2))) float f32x2;

#define BATCH 32
#define CIN   96
#define LSEQ  4096
#define DIN   256
#define NST   16
#define MROWS (BATCH * LSEQ)   // 131072

__device__ __forceinline__ float b2f(u16 u) {
    union { unsigned int i; float f; } v; v.i = ((unsigned int)u) << 16; return v.f;
}
__device__ __forceinline__ u16 f2b(float f) {
    union { float f; unsigned int i; } v; v.f = f;
    unsigned int i = v.i;
    unsigned int lsb = (i >> 16) & 1u;
    return (u16)((i + 0x7fffu + lsb) >> 16);
}
__device__ __forceinline__ float ldv(const u16* p)   { return b2f(*p); }
__device__ __forceinline__ float ldv(const float* p) { return *p; }
__device__ __forceinline__ void stv(u16* p, float v)   { *p = f2b(v); }
__device__ __forceinline__ void stv(float* p, float v) { *p = v; }

__device__ __forceinline__ void ld8(const u16* p, float* f) {
    short8 v = *(const short8*)p;
    #pragma unroll
    for (int e = 0; e < 8; e++) f[e] = b2f((u16)v[e]);
}
__device__ __forceinline__ void ld8(const float* p, float* f) {
    f32x4 a = *(const f32x4*)p; f32x4 b = *(const f32x4*)(p + 4);
    f[0]=a[0]; f[1]=a[1]; f[2]=a[2]; f[3]=a[3];
    f[4]=b[0]; f[5]=b[1]; f[6]=b[2]; f[7]=b[3];
}

// ---------------------------------------------------------------------------
// K0: fp32 -> bf16 conversion for MFMA weight operands
// ---------------------------------------------------------------------------
__global__ __launch_bounds__(256) void k0_cvt(
    const float* __restrict__ src, u16* __restrict__ dst, int n)
{
    int i = blockIdx.x * 256 + threadIdx.x;
    if (i < n) dst[i] = f2b(src[i]);
}

// ---------------------------------------------------------------------------
// K1: xz[m, 0:512] = h_in[m, 0:96] @ in_proj_w^T + b ; h_in[b*L+l, c] = x[b,c,l]
// ---------------------------------------------------------------------------
__global__ __launch_bounds__(256) void k1_inproj(
    const float* __restrict__ x, const u16* __restrict__ wp,
    const float* __restrict__ bias, u16* __restrict__ xz)
{
    __shared__ u16 AtT[64 * 104];
    int m0 = blockIdx.x * 64;
    int b  = m0 >> 12;
    int l0 = m0 & 4095;
    int n0 = blockIdx.y * 256;
    int t  = threadIdx.x;
    {
        int i = t & 63, c0 = t >> 6;
        for (int c = c0; c < 96; c += 4)
            AtT[i * 104 + c] = f2b(x[((size_t)(b * 96 + c)) * 4096 + l0 + i]);
    }
    __syncthreads();
    int lane = t & 63, wid = t >> 6, q = lane >> 4, ml = lane & 15;
    f32x4 acc[16];
    #pragma unroll
    for (int f = 0; f < 16; f++)
        #pragma unroll
        for (int r = 0; r < 4; r++) acc[f][r] = 0.f;
    int arow = wid * 16 + ml;
    for (int k0 = 0; k0 < 96; k0 += 32) {
        int kb = k0 + q * 8;
        short8 a = *(const short8*)&AtT[arow * 104 + kb];
        #pragma unroll
        for (int f = 0; f < 16; f++) {
            int n = n0 + f * 16 + ml;
            short8 bf = *(const short8*)&wp[(size_t)n * 96 + kb];
            acc[f] = __builtin_amdgcn_mfma_f32_16x16x32_bf16(a, bf, acc[f], 0, 0, 0);
        }
    }
    #pragma unroll
    for (int f = 0; f < 16; f++) {
        int n = n0 + f * 16 + ml;
        float bs = bias[n];
        #pragma unroll
        for (int r = 0; r < 4; r++) {
            int m = m0 + wid * 16 + q * 4 + r;
            xz[(size_t)m * 512 + n] = f2b(acc[f][r] + bs);
        }
    }
}

// ---------------------------------------------------------------------------
// K3f: FUSED conv + x_proj (verified bit-exact vs the split path in rounds
// 1/3). Per 64-row tile: u = silu(depthwise causal conv) -> LDS AND global;
// dtbc = u @ x_proj_w^T from LDS; dt = softplus(...) -> global fp32.
// Scan pass A stays in k4 (rounds 4/5: relocating it fails the absmax gate).
// ---------------------------------------------------------------------------
template<typename DT>
__global__ __launch_bounds__(256) void k3_convxproj(
    const u16* __restrict__ xz, const float* __restrict__ cw,
    const float* __restrict__ cb, const u16* __restrict__ xw,
    const float* __restrict__ dw, const float* __restrict__ db,
    u16* __restrict__ u, DT* __restrict__ dt,
    float* __restrict__ Bb, float* __restrict__ Cb)
{
    __shared__ u16 Us[64 * 264];        // 33792 B
    __shared__ float dtbc[64][49];      // 12544 B
    int m0 = blockIdx.x * 64;
    int b  = m0 >> 12;
    int l0 = m0 & 4095;
    int d  = threadIdx.x;
    {   // conv: thread d = channel, 64 rows serial (3-reg shift), halo from xz
        float w0 = cw[d * 4 + 0], w1 = cw[d * 4 + 1];
        float w2 = cw[d * 4 + 2], w3 = cw[d * 4 + 3];
        float bias = cb[d];
        size_t rowbase = ((size_t)b * 4096) * 512 + d;
        size_t ubase   = ((size_t)b * 4096 + l0) * 256 + d;
        float x0 = (l0 >= 3) ? b2f(xz[rowbase + (size_t)(l0 - 3) * 512]) : 0.f;
        float x1 = (l0 >= 2) ? b2f(xz[rowbase + (size_t)(l0 - 2) * 512]) : 0.f;
        float x2 = (l0 >= 1) ? b2f(xz[rowbase + (size_t)(l0 - 1) * 512]) : 0.f;
        #pragma unroll 8
        for (int i = 0; i < 64; i++) {
            float x3 = b2f(xz[rowbase + (size_t)(l0 + i) * 512]);
            float sv = w0 * x0 + w1 * x1 + w2 * x2 + w3 * x3 + bias;
            float sig = 1.f / (1.f + __expf(-sv));
            u16 bv = f2b(sv * sig);
            Us[i * 264 + d] = bv;
            u[ubase + (size_t)i * 256] = bv;
            x0 = x1; x1 = x2; x2 = x3;
        }
    }
    __syncthreads();
    int lane = d & 63, wid = d >> 6, q = lane >> 4, ml = lane & 15;
    f32x4 acc[3];
    #pragma unroll
    for (int f = 0; f < 3; f++)
        #pragma unroll
        for (int r = 0; r < 4; r++) acc[f][r] = 0.f;
    int arow = wid * 16 + ml;
    #pragma unroll
    for (int k0 = 0; k0 < 256; k0 += 32) {
        int kb = k0 + q * 8;
        short8 a = *(const short8*)&Us[arow * 264 + kb];
        #pragma unroll
        for (int f = 0; f < 3; f++) {
            short8 bf = *(const short8*)&xw[(size_t)(f * 16 + ml) * 256 + kb];
            acc[f] = __builtin_amdgcn_mfma_f32_16x16x32_bf16(a, bf, acc[f], 0, 0, 0);
        }
    }
    #pragma unroll
    for (int f = 0; f < 3; f++)
        #pragma unroll
        for (int r = 0; r < 4; r++)
            dtbc[wid * 16 + q * 4 + r][f * 16 + ml] = acc[f][r];
    __syncthreads();
    {   // B, C writes
        int row = d >> 5, cc = d & 31;
        for (int p = 0; p < 8; p++) {
            int rr = row + p * 8;
            float v = dtbc[rr][16 + cc];
            size_t idx = (size_t)(m0 + rr) * 16 + (cc & 15);
            if (cc < 16) Bb[idx] = v; else Cb[idx] = v;
        }
    }
    {   // dt: thread = d
        float wr[16];
        #pragma unroll
        for (int j = 0; j < 16; j++) wr[j] = dw[d * 16 + j];
        float bias = db[d];
        for (int r = 0; r < 64; r++) {
            float s = bias;
            #pragma unroll
            for (int j = 0; j < 16; j++) s += dtbc[r][j] * wr[j];
            float sp = (s > 20.f) ? s : __logf(1.f + __expf(s));
            stv(&dt[(size_t)(m0 + r) * 256 + d], sp);
        }
    }
}

// ---------------------------------------------------------------------------
// K4: scan pass A — per chunk: local final state (h from 0) + sum of dt.
// ---------------------------------------------------------------------------
template<typename DT>
__global__ __launch_bounds__(256) void k4_scanA(
    const DT* __restrict__ dt, const u16* __restrict__ u,
    const float* __restrict__ Bb, const float* __restrict__ alog,
    float* __restrict__ hloc, float* __restrict__ sdt, int lchunk)
{
    __shared__ float Bs[128 * 16];
    int s = blockIdx.x, b = blockIdx.y;
    int l0 = s * lchunk;
    int d = threadIdx.x;
    float Af[16];
    bool structured = true;
    #pragma unroll
    for (int n = 0; n < 16; n++) {
        Af[n] = -__expf(alog[d * 16 + n]);
        structured = structured && (fabsf(Af[n] + (float)(n + 1)) <= 1e-3f * (n + 1));
    }
    const float* bsrc = &Bb[((size_t)b * 4096 + l0) * 16];
    for (int jj = threadIdx.x; jj < lchunk * 16; jj += 256) Bs[jj] = bsrc[jj];
    __syncthreads();
    size_t base = ((size_t)b * 4096 + l0) * 256 + d;
    size_t o = (((size_t)s * 32 + b) * 256 + d) * 16;
    float sd = 0.f;
    if (structured) {
        f32x2 h2[8];
        #pragma unroll
        for (int k = 0; k < 8; k++) h2[k] = (f32x2){0.f, 0.f};
        for (int i = 0; i < lchunk; i++) {
            float dtv = ldv(&dt[base + (size_t)i * 256]);
            float uv  = b2f(u[base + (size_t)i * 256]);
            sd += dtv;
            float du = dtv * uv;
            float e1 = __expf(-dtv);
            float e1s = e1 * e1;
            f32x2 e2 = (f32x2){e1s, e1s};
            f32x2 p  = (f32x2){e1, e1s};
            f32x2 du2 = (f32x2){du, du};
            const f32x2* B2 = (const f32x2*)&Bs[i * 16];
            #pragma unroll
            for (int k = 0; k < 8; k++) {
                h2[k] = p * h2[k] + du2 * B2[k];
                p = p * e2;
            }
        }
        #pragma unroll
        for (int k = 0; k < 8; k++) *(f32x2*)&hloc[o + 2 * k] = h2[k];
    } else {
        float h[16];
        #pragma unroll
        for (int n = 0; n < 16; n++) h[n] = 0.f;
        for (int i = 0; i < lchunk; i++) {
            float dtv = ldv(&dt[base + (size_t)i * 256]);
            float uv  = b2f(u[base + (size_t)i * 256]);
            sd += dtv;
            float du = dtv * uv;
            #pragma unroll
            for (int n = 0; n < 16; n++) {
                float dA = __expf(dtv * Af[n]);
                h[n] = dA * h[n] + du * Bs[i * 16 + n];
            }
        }
        #pragma unroll
        for (int n = 0; n < 16; n++) hloc[o + n] = h[n];
    }
    sdt[((size_t)s * 32 + b) * 256 + d] = sd;
}

// ---------------------------------------------------------------------------
// K5: carry combine across chunks per (b,d,n). hin aliases hloc (in-place:
// per element, hloc is read before hin is written by the same thread).
// Verified passing in rounds 1 and 3.
// ---------------------------------------------------------------------------
__global__ __launch_bounds__(256) void k5_scanB(
    const float* __restrict__ hloc, const float* __restrict__ sdt,
    const float* __restrict__ alog, float* __restrict__ hin, int nch)
{
    int t = blockIdx.x * 256 + threadIdx.x;   // (b, d, n)
    int b = t >> 12;
    int rem = t & 4095;                        // d*16 + n
    int d = rem >> 4;
    float A = -__expf(alog[rem]);
    float h = 0.f;
    for (int s = 0; s < nch; s++) {
        size_t o = ((size_t)(s * 32 + b)) * 4096 + rem;
        float hl = hloc[o];
        float sd = sdt[((size_t)(s * 32 + b)) * 256 + d];
        hin[o] = h;
        h = __expf(A * sd) * h + hl;
    }
}

// ---------------------------------------------------------------------------
// K6: scan pass C — true scan with carry-in; fuse y+u*D, *silu(z), +x_res.
// Writes pre-LN1 tensor t (u16, in-place over u).
// ---------------------------------------------------------------------------
template<typename DT, typename TT>
__global__ __launch_bounds__(256) void k6_scanC(
    const DT* __restrict__ dt, const u16* __restrict__ u,
    const float* __restrict__ Bb, const float* __restrict__ Cb,
    const float* __restrict__ alog, const float* __restrict__ hin,
    const u16* __restrict__ xz, const float* __restrict__ Dp,
    TT* __restrict__ tp, int lchunk)
{
    __shared__ float Bs[128 * 16];
    __shared__ float Cs[128 * 16];
    int s = blockIdx.x, b = blockIdx.y;
    int l0 = s * lchunk;
    int d = threadIdx.x;
    float Af[16];
    bool structured = true;
    #pragma unroll
    for (int n = 0; n < 16; n++) {
        Af[n] = -__expf(alog[d * 16 + n]);
        structured = structured && (fabsf(Af[n] + (float)(n + 1)) <= 1e-3f * (n + 1));
    }
    {
        const float* bsrc = &Bb[((size_t)b * 4096 + l0) * 16];
        const float* csrc = &Cb[((size_t)b * 4096 + l0) * 16];
        for (int jj = threadIdx.x; jj < lchunk * 16; jj += 256) {
            Bs[jj] = bsrc[jj]; Cs[jj] = csrc[jj];
        }
    }
    __syncthreads();
    size_t o = (((size_t)s * 32 + b) * 256 + d) * 16;
    float Dv = Dp[d];
    size_t base  = ((size_t)b * 4096 + l0) * 256 + d;
    size_t zbase = ((size_t)b * 4096 + l0) * 512 + d;
    if (structured) {
        f32x2 h2[8];
        #pragma unroll
        for (int k = 0; k < 8; k++) h2[k] = *(const f32x2*)&hin[o + 2 * k];
        for (int i = 0; i < lchunk; i++) {
            float dtv = ldv(&dt[base + (size_t)i * 256]);
            float uv  = b2f(u[base + (size_t)i * 256]);
            float du = dtv * uv;
            float e1 = __expf(-dtv);
            float e1s = e1 * e1;
            f32x2 e2 = (f32x2){e1s, e1s};
            f32x2 p  = (f32x2){e1, e1s};
            f32x2 du2 = (f32x2){du, du};
            f32x2 y2 = (f32x2){0.f, 0.f};
            const f32x2* B2 = (const f32x2*)&Bs[i * 16];
            const f32x2* C2 = (const f32x2*)&Cs[i * 16];
            #pragma unroll
            for (int k = 0; k < 8; k++) {
                h2[k] = p * h2[k] + du2 * B2[k];
                y2 = y2 + h2[k] * C2[k];
                p = p * e2;
            }
            float y = y2[0] + y2[1] + uv * Dv;
            float zv = b2f(xz[zbase + (size_t)i * 512 + 256]);
            float xr = b2f(xz[zbase + (size_t)i * 512]);
            float sig = 1.f / (1.f + __expf(-zv));
            y *= zv * sig;
            stv(&tp[base + (size_t)i * 256], y + xr);
        }
    } else {
        float h[16];
        #pragma unroll
        for (int n = 0; n < 16; n++) h[n] = hin[o + n];
        for (int i = 0; i < lchunk; i++) {
            float dtv = ldv(&dt[base + (size_t)i * 256]);
            float uv  = b2f(u[base + (size_t)i * 256]);
            float du = dtv * uv;
            float y = 0.f;
            #pragma unroll
            for (int n = 0; n < 16; n++) {
                float dA = __expf(dtv * Af[n]);
                h[n] = dA * h[n] + du * Bs[i * 16 + n];
                y += h[n] * Cs[i * 16 + n];
            }
            y += uv * Dv;
            float zv = b2f(xz[zbase + (size_t)i * 512 + 256]);
            float xr = b2f(xz[zbase + (size_t)i * 512]);
            float sig = 1.f / (1.f + __expf(-zv));
            y *= zv * sig;
            stv(&tp[base + (size_t)i * 256], y + xr);
        }
    }
}

// ---------------------------------------------------------------------------
// K8: y1 = LN1(t); y_proj = y1 @ out_proj_w^T + ob; out = LN2(y1 + y_proj).
// ROUND-0 VERBATIM (unswizzled Yt[64*272], plain launch bounds). The
// XOR-swizzled variant is banned: mathematically value-identical, but the
// no-spill compile of it failed the absmax gate 4/4 times (rounds 4-7) with
// varying error — codegen-level corruption; the spilled compile (rounds 2/3)
// and this unswizzled form (round 0) both passed.
// ---------------------------------------------------------------------------
template<typename TT>
__global__ __launch_bounds__(256) void k8_final(
    const TT* __restrict__ tb, const u16* __restrict__ ow,
    const float* __restrict__ ob, const float* __restrict__ g1,
    const float* __restrict__ bb1, const float* __restrict__ g2,
    const float* __restrict__ bb2, float* __restrict__ out)
{
    __shared__ u16 Yt[64 * 272];
    int m0 = blockIdx.x * 64;
    int t  = threadIdx.x;
    {   // LN1 (4 threads per row, shuffle-combine partials)
        int r = t >> 2, ccol = (t & 3) * 64;
        const TT* src = &tb[(size_t)(m0 + r) * 256 + ccol];
        u16* dst = &Yt[r * 272 + ccol];
        float sum = 0.f, sq = 0.f;
        for (int jj = 0; jj < 64; jj += 8) {
            float f[8]; ld8(src + jj, f);
            #pragma unroll
            for (int e = 0; e < 8; e++) { sum += f[e]; sq += f[e] * f[e]; }
        }
        sum += __shfl_xor(sum, 1); sq += __shfl_xor(sq, 1);
        sum += __shfl_xor(sum, 2); sq += __shfl_xor(sq, 2);
        float mean = sum * (1.f / 256.f);
        float var  = sq * (1.f / 256.f) - mean * mean;
        float rstd = rsqrtf(var + 1e-5f);
        for (int jj = 0; jj < 64; jj += 8) {
            float f[8]; ld8(src + jj, f);
            #pragma unroll
            for (int e = 0; e < 8; e++) {
                int c = ccol + jj + e;
                dst[jj + e] = f2b((f[e] - mean) * rstd * g1[c] + bb1[c]);
            }
        }
    }
    __syncthreads();
    int lane = t & 63, wid = t >> 6, q = lane >> 4, ml = lane & 15;
    f32x4 acc[16];
    #pragma unroll
    for (int f = 0; f < 16; f++)
        #pragma unroll
        for (int r = 0; r < 4; r++) acc[f][r] = 0.f;
    int arow = wid * 16 + ml;
    #pragma unroll
    for (int k0 = 0; k0 < 256; k0 += 32) {
        short8 a = *(const short8*)&Yt[arow * 272 + k0 + q * 8];
        #pragma unroll
        for (int f = 0; f < 16; f++) {
            short8 bf = *(const short8*)&ow[(size_t)(f * 16 + ml) * 256 + k0 + q * 8];
            acc[f] = __builtin_amdgcn_mfma_f32_16x16x32_bf16(a, bf, acc[f], 0, 0, 0);
        }
    }
    float ps[4] = {0, 0, 0, 0}, psq[4] = {0, 0, 0, 0};
    #pragma unroll
    for (int f = 0; f < 16; f++) {
        int col = f * 16 + ml;
        float obv = ob[col];
        #pragma unroll
        for (int r = 0; r < 4; r++) {
            int row = wid * 16 + q * 4 + r;
            float v = acc[f][r] + obv + b2f(Yt[row * 272 + col]);
            acc[f][r] = v;
            ps[r] += v; psq[r] += v * v;
        }
    }
    #pragma unroll
    for (int msk = 1; msk < 16; msk <<= 1) {
        #pragma unroll
        for (int r = 0; r < 4; r++) {
            ps[r]  += __shfl_xor(ps[r],  msk);
            psq[r] += __shfl_xor(psq[r], msk);
        }
    }
    #pragma unroll
    for (int f = 0; f < 16; f++) {
        int col = f * 16 + ml;
        float g2v = g2[col], b2v = bb2[col];
        #pragma unroll
        for (int r = 0; r < 4; r++) {
            int row = wid * 16 + q * 4 + r;
            float mean = ps[r] * (1.f / 256.f);
            float var  = psq[r] * (1.f / 256.f) - mean * mean;
            float rstd = rsqrtf(var + 1e-5f);
            out[(size_t)(m0 + row) * 256 + col] = (acc[f][r] - mean) * rstd * g2v + b2v;
        }
    }
}

extern "C" void kernel_launch(void* const* d_in, const int* in_sizes, int n_in,
                              void* d_out, int out_size, void* d_ws, size_t ws_size,
                              hipStream_t stream)
{
    const float* x    = (const float*)d_in[0];
    const float* ipw  = (const float*)d_in[1];
    const float* ipb  = (const float*)d_in[2];
    const float* cw   = (const float*)d_in[3];
    const float* cb   = (const float*)d_in[4];
    const float* xpw  = (const float*)d_in[5];
    const float* dpw  = (const float*)d_in[6];
    const float* dpb  = (const float*)d_in[7];
    const float* opw  = (const float*)d_in[8];
    const float* opb  = (const float*)d_in[9];
    const float* alog = (const float*)d_in[10];
    const float* Dp   = (const float*)d_in[11];
    const float* g1   = (const float*)d_in[12];
    const float* b1   = (const float*)d_in[13];
    const float* g2   = (const float*)d_in[14];
    const float* b2   = (const float*)d_in[15];
    float* outp = (float*)d_out;

    char* ws = (char*)d_ws;
    u16*   xz  = (u16*)ws;                          // 134217728 B
    u16*   u   = (u16*)(ws + 134217728);            //  67108864 B
    float* Bb  = (float*)(ws + 201326592);          //   8388608 B
    float* Cb  = (float*)(ws + 209715200);          //   8388608 B
    u16* ipw_b = (u16*)(ws + 218103808);            // 49152 el
    u16* xpw_b = ipw_b + 49152;                     // 12288 el
    u16* opw_b = xpw_b + 12288;                     // 65536 el
    const size_t wbase = 218103808 + 262144;        // weights padded

    k0_cvt<<<192, 256, 0, stream>>>(ipw, ipw_b, 49152);
    k0_cvt<<<48,  256, 0, stream>>>(xpw, xpw_b, 12288);
    k0_cvt<<<256, 256, 0, stream>>>(opw, opw_b, 65536);
    k1_inproj<<<dim3(2048, 2), 256, 0, stream>>>(x, ipw_b, ipb, xz);

    // scan scratch with in-place carry (hin aliases hloc): hloc + sdt only
    const size_t scan64 = (size_t)64 * 524288 + (size_t)64 * 32768;   // 35.6 MB

    // Numerics pinned to the verified path: fp32 dt -> k4 -> k6 -> bf16 t
    // in-place over u -> k8<u16> (absmax 0.1914, rounds 0/3). Fallback tiers
    // keep fp32 dt — bf16-dt forks are numerically unsafe.
    if (ws_size >= wbase + 134217728 + scan64) {
        // NC=64, fp32 dt  (selected on this harness: ws in [522, 556) MB)
        float* dt   = (float*)(ws + wbase);
        float* hloc = (float*)(ws + wbase + 134217728);
        float* sdt  = hloc + (size_t)64 * 131072;
        k3_convxproj<float><<<2048, 256, 0, stream>>>(xz, cw, cb, xpw_b, dpw, dpb, u, dt, Bb, Cb);
        k4_scanA<float><<<dim3(64, 32), 256, 0, stream>>>(dt, u, Bb, alog, hloc, sdt, 64);
        k5_scanB<<<512, 256, 0, stream>>>(hloc, sdt, alog, hloc, 64);
        k6_scanC<float, u16><<<dim3(64, 32), 256, 0, stream>>>(dt, u, Bb, Cb, alog, hloc, xz, Dp, u, 64);
        k8_final<u16><<<2048, 256, 0, stream>>>(u, opw_b, opb, g1, b1, g2, b2, outp);
    } else {
        // NC=32, fp32 dt (smaller scan scratch; same verified numerics class)
        float* dt   = (float*)(ws + wbase);
        float* hloc = (float*)(ws + wbase + 134217728);
        float* sdt  = hloc + (size_t)32 * 131072;
        k3_convxproj<float><<<2048, 256, 0, stream>>>(xz, cw, cb, xpw_b, dpw, dpb, u, dt, Bb, Cb);
        k4_scanA<float><<<dim3(32, 32), 256, 0, stream>>>(dt, u, Bb, alog, hloc, sdt, 128);
        k5_scanB<<<512, 256, 0, stream>>>(hloc, sdt, alog, hloc, 32);
        k6_scanC<float, u16><<<dim3(32, 32), 256, 0, stream>>>(dt, u, Bb, Cb, alog, hloc, xz, Dp, u, 128);
        k8_final<u16><<<2048, 256, 0, stream>>>(u, opw_b, opb, g1, b1, g2, b2, outp);
    }
}